// Round 5
// baseline (226.064 us; speedup 1.0000x reference)
//
#include <hip/hip_runtime.h>
#include <cstdint>

// FCOS post-processor, exact-semantics port of the JAX reference.
// N=32 images, C=1, H=100, W=168 -> 16800 locations; PRE_NMS=1000, POST=100.
//
//   K1 fcos_topk : per-image exact top-1000 (radix-select on unique 48-bit keys
//                  = sortable(sigmoid_f32) << 16 | (0xFFFF - idx)) + hybrid
//                  shfl/LDS bitonic sort + box decode/clip/validity.
//   K2 fcos_mask : pairwise IoU -> 64-bit suppression words, LOWER triangle +
//                  diagonal words only (IoU matrix is exactly symmetric; the
//                  scan only reads words c <= row/64).
//   K3 fcos_scan : kept-only greedy NMS (serial work per KEPT box, not per
//                  row), then emit top-100.

typedef unsigned long long u64;
typedef unsigned int u32;

#define HW_TOT 16800
#define W_GRID 168
#define K_PRE  1000
#define NRANK  1024
#define N_IMG  32

// ws layout (bytes)
#define SCORES_OFF 0
#define VALID_OFF  (N_IMG * NRANK * 4)
#define BOXES_OFF  (VALID_OFF + N_IMG * NRANK * 4)
#define MASK_OFF   (BOXES_OFF + N_IMG * NRANK * 16)
#define WS_NEED    ((size_t)MASK_OFF + (size_t)N_IMG * NRANK * 16 * 8)

// ---------------------------------------------------------------- kernel 1
__global__ __launch_bounds__(1024) void fcos_topk(
    const float* __restrict__ box_cls, const float* __restrict__ box_reg,
    const int* __restrict__ imh, const int* __restrict__ imw,
    float* __restrict__ scores_ws, u32* __restrict__ valid_ws,
    float* __restrict__ boxes_ws)
{
  const int n = blockIdx.x;
  const int t = threadIdx.x;
  const int lane = t & 63;
  __shared__ u32 hist[256];
  __shared__ u64 prefix_s;
  __shared__ u32 kneed_s, cnt_s;
  __shared__ u64 skey[1024];

  // Unique 48-bit keys; sigmoid in f64 then rounded (matches ref bit-exactly,
  // absmax was 0.0). Low 16 bits 0xFFFF-idx => desc key order == lax.top_k.
  u64 kreg[17];
  const float* cls = box_cls + (size_t)n * HW_TOT;
  #pragma unroll
  for (int k = 0; k < 17; ++k) {
    int i = t + k * 1024;
    u64 key = 0;
    if (i < HW_TOT) {
      float x = cls[i];
      double sd = 1.0 / (1.0 + exp(-(double)x));
      float s = (float)sd;
      u32 b = __float_as_uint(s);
      u32 u = (b & 0x80000000u) ? ~b : (b | 0x80000000u);
      key = ((u64)u << 16) | (u64)(0xFFFFu - (u32)i);
    }
    kreg[k] = key;
  }
  if (t == 0) { prefix_s = 0ull; kneed_s = K_PRE; cnt_s = 0u; }
  __syncthreads();

  // 6-pass MSB radix select, wave-aggregated histogram + wave-0 suffix scan.
  for (int p = 5; p >= 0; --p) {
    if (t < 256) hist[t] = 0u;
    __syncthreads();
    const u64 pref = prefix_s;
    const int sh = p * 8;
    #pragma unroll
    for (int k = 0; k < 17; ++k) {
      u64 key = kreg[k];
      bool act = ((key >> (sh + 8)) == pref);
      u32 bin = (u32)((key >> sh) & 0xFFull);
      u64 rem = __ballot(act);
      while (rem) {
        int leader = __ffsll((long long)rem) - 1;
        u32 lbin = __shfl(bin, leader);
        u64 same = __ballot(act && (bin == lbin));
        if (lane == leader) atomicAdd(&hist[lbin], (u32)__popcll(same));
        rem &= ~same;
        act = act && (bin != lbin);
      }
    }
    __syncthreads();
    if (t < 64) {  // inclusive suffix sum over 256 bins, single wave
      u32 h0 = hist[4*t], h1 = hist[4*t+1], h2 = hist[4*t+2], h3 = hist[4*t+3];
      u32 bs = h0 + h1 + h2 + h3, s = bs;
      #pragma unroll
      for (int off = 1; off < 64; off <<= 1) {
        u32 tmp = __shfl_down(s, off);
        if (t + off < 64) s += tmp;
      }
      u32 tail = s - bs;
      hist[4*t+3] = h3 + tail;
      hist[4*t+2] = h2 + h3 + tail;
      hist[4*t+1] = h1 + h2 + h3 + tail;
      hist[4*t]   = bs + tail;
    }
    __syncthreads();
    bool sel = false; u32 kn = 0, gt = 0;
    if (t < 256) {
      u32 ge = hist[t];
      gt = (t < 255) ? hist[t + 1] : 0u;
      kn = kneed_s;
      sel = (ge >= kn) && (gt < kn);
    }
    const u64 curp = prefix_s;
    __syncthreads();
    if (sel) { prefix_s = (curp << 8) | (u64)t; kneed_s = kn - gt; }
    __syncthreads();
  }

  // Compact keys >= T (unique keys -> exactly 1000), pad 0.
  const u64 T = prefix_s;
  skey[t] = 0ull;
  __syncthreads();
  #pragma unroll
  for (int k = 0; k < 17; ++k) {
    if (kreg[k] >= T) {
      u32 pos = atomicAdd(&cnt_s, 1u);
      if (pos < 1024u) skey[pos] = kreg[k];
    }
  }
  __syncthreads();

  // Hybrid bitonic sort desc: intra-wave steps via shfl_xor (no barriers),
  // cross-wave steps (j>=64) via LDS (2 barriers each, 10 total).
  u64 key = skey[t];
  #pragma unroll
  for (u32 k2 = 2; k2 <= 64; k2 <<= 1) {
    #pragma unroll
    for (u32 j = k2 >> 1; j > 0; j >>= 1) {
      u64 other = __shfl_xor(key, (int)j);
      bool takeMax = (((t & k2) == 0) == ((t & j) == 0));
      u64 mx = key > other ? key : other;
      u64 mn = key > other ? other : key;
      key = takeMax ? mx : mn;
    }
  }
  #pragma unroll
  for (u32 k2 = 128; k2 <= 1024; k2 <<= 1) {
    for (u32 j = k2 >> 1; j >= 64; j >>= 1) {
      skey[t] = key;
      __syncthreads();
      u64 other = skey[t ^ j];
      __syncthreads();
      bool takeMax = (((t & k2) == 0) == ((t & j) == 0));
      u64 mx = key > other ? key : other;
      u64 mn = key > other ? other : key;
      key = takeMax ? mx : mn;
    }
    #pragma unroll
    for (u32 j = 32; j > 0; j >>= 1) {
      u64 other = __shfl_xor(key, (int)j);
      bool takeMax = (((t & k2) == 0) == ((t & j) == 0));
      u64 mx = key > other ? key : other;
      u64 mn = key > other ? other : key;
      key = takeMax ? mx : mn;
    }
  }

  // Decode rank t (from register key).
  const float fw = (float)(*imw) - 1.0f;
  const float fh = (float)(*imh) - 1.0f;
  float* bx = boxes_ws + ((size_t)n * NRANK + t) * 4;
  if (t < K_PRE) {
    u32 u = (u32)(key >> 16);
    u32 b = (u & 0x80000000u) ? (u & 0x7FFFFFFFu) : ~u;
    float s = __uint_as_float(b);
    u32 idx = 0xFFFFu - (u32)(key & 0xFFFFull);
    int hh = (int)idx / W_GRID, ww = (int)idx - hh * W_GRID;
    float lx = (float)(ww * 8 + 4), ly = (float)(hh * 8 + 4);
    const float* rg = box_reg + (size_t)n * 4 * HW_TOT + idx;
    float r0 = rg[0], r1 = rg[HW_TOT], r2 = rg[2 * HW_TOT], r3 = rg[3 * HW_TOT];
    float x1 = fminf(fmaxf(lx - r0, 0.0f), fw);
    float y1 = fminf(fmaxf(ly - r1, 0.0f), fh);
    float x2 = fminf(fmaxf(lx + r2, 0.0f), fw);
    float y2 = fminf(fmaxf(ly + r3, 0.0f), fh);
    bool valid = (s > 0.01f) && ((x2 - x1 + 1.0f) >= 0.0f)
                             && ((y2 - y1 + 1.0f) >= 0.0f);   // MIN_SIZE = 0
    scores_ws[n * NRANK + t] = s;
    valid_ws[n * NRANK + t] = valid ? 1u : 0u;
    bx[0] = x1; bx[1] = y1; bx[2] = x2; bx[3] = y2;
  } else {
    scores_ws[n * NRANK + t] = 0.0f;
    valid_ws[n * NRANK + t] = 0u;
    bx[0] = 0.0f; bx[1] = 0.0f; bx[2] = 0.0f; bx[3] = 0.0f;
  }
}

// ---------------------------------------------------------------- kernel 2
// Lower-triangle + diagonal words only: word c of row i computed iff c <= i>>6.
// (IoU is exactly symmetric, min/max/add/div commute bitwise; scan reads only
// words c <= i>>6 of each row.) Rows interleaved mod 8 for block balance.
__global__ __launch_bounds__(1024) void fcos_mask(
    const float* __restrict__ boxes_ws, u64* __restrict__ mask_ws)
{
  const int n = blockIdx.y, g = blockIdx.x;   // g < 8
  const int t = threadIdx.x;
  __shared__ float4 bx[1024];
  bx[t] = ((const float4*)boxes_ws)[(size_t)n * NRANK + t];
  __syncthreads();
  const int wv = t >> 6, lane = t & 63;
  u64* mimg = mask_ws + (size_t)n * NRANK * 16;
  for (int r = wv; r < 125; r += 16) {
    const int i = r * 8 + g;                  // covers 0..999 exactly once
    const float4 bi = bx[i];
    const float ai = __fmul_rn(fmaxf(bi.z - bi.x, 0.0f), fmaxf(bi.w - bi.y, 0.0f));
    const int cmax = i >> 6;
    for (int c = 0; c <= cmax; ++c) {
      const int j = c * 64 + lane;
      const float4 bj = bx[j];
      const float aj = __fmul_rn(fmaxf(bj.z - bj.x, 0.0f), fmaxf(bj.w - bj.y, 0.0f));
      float iw  = fmaxf(fminf(bi.z, bj.z) - fmaxf(bi.x, bj.x), 0.0f);
      float ih2 = fmaxf(fminf(bi.w, bj.w) - fmaxf(bi.y, bj.y), 0.0f);
      float inter = __fmul_rn(iw, ih2);
      float uni = fmaxf(__fsub_rn(__fadd_rn(ai, aj), inter), 1e-9f);
      float iou = inter / uni;
      u64 m = __ballot(iou > 0.5f);
      if (lane == 0) mimg[(size_t)i * 16 + c] = m;
    }
  }
}

// ---------------------------------------------------------------- kernel 3
// Kept-only greedy scan. Lane j holds the full mask row of box blk*64+j
// (16 u64, 128B coalesced, double-buffered). Per block: one ballot computes
// the live word from earlier kept words; then a serial loop only over KEPT
// boxes: ctz -> shfl diag word -> clear.
__global__ __launch_bounds__(64) void fcos_scan(
    const float* __restrict__ scores_ws, const u32* __restrict__ valid_ws,
    const float* __restrict__ boxes_ws, const u64* __restrict__ mask_ws,
    float* __restrict__ out)
{
  const int n = blockIdx.x;
  const int lane = threadIdx.x;
  const u64* mbase = mask_ws + (size_t)n * NRANK * 16;

  u64 vw[16];
  #pragma unroll
  for (int w = 0; w < 16; ++w)
    vw[w] = __ballot(valid_ws[n * NRANK + w * 64 + lane] != 0u);

  u64 keptw[16];
  #pragma unroll
  for (int w = 0; w < 16; ++w) keptw[w] = 0ull;

  ulonglong2 A2[8], B2[8];
#define WORD(ARR, w) ((w) & 1 ? ARR[(w) >> 1].y : ARR[(w) >> 1].x)
#define LOADBLK(DST, BLK) do { \
    const ulonglong2* _p = (const ulonglong2*)(mbase + (((size_t)(BLK)) * 64 + (size_t)lane) * 16); \
    _Pragma("unroll") \
    for (int _r = 0; _r < 8; ++_r) DST[_r] = _p[_r]; \
  } while (0)
#define PROCBLK(ARR, BV) do { \
    u64 _acc = 0ull; \
    _Pragma("unroll") \
    for (int _w = 0; _w < 16; ++_w) \
      if (_w < (BV)) _acc |= WORD(ARR, _w) & keptw[_w]; \
    u64 _live = vw[(BV)] & ~__ballot(_acc != 0ull); \
    const u64 _intra = WORD(ARR, (BV)); \
    u64 _kb = 0ull; \
    while (_live) { \
      int _i = __ffsll((long long)_live) - 1; \
      _kb |= (1ull << _i); \
      u64 _r = __shfl(_intra, _i); \
      _live &= ~(_r | (1ull << _i)); \
    } \
    keptw[(BV)] = _kb; \
  } while (0)

  LOADBLK(A2, 0);
  LOADBLK(B2, 1);   PROCBLK(A2, 0);
  LOADBLK(A2, 2);   PROCBLK(B2, 1);
  LOADBLK(B2, 3);   PROCBLK(A2, 2);
  LOADBLK(A2, 4);   PROCBLK(B2, 3);
  LOADBLK(B2, 5);   PROCBLK(A2, 4);
  LOADBLK(A2, 6);   PROCBLK(B2, 5);
  LOADBLK(B2, 7);   PROCBLK(A2, 6);
  LOADBLK(A2, 8);   PROCBLK(B2, 7);
  LOADBLK(B2, 9);   PROCBLK(A2, 8);
  LOADBLK(A2, 10);  PROCBLK(B2, 9);
  LOADBLK(B2, 11);  PROCBLK(A2, 10);
  LOADBLK(A2, 12);  PROCBLK(B2, 11);
  LOADBLK(B2, 13);  PROCBLK(A2, 12);
  LOADBLK(A2, 14);  PROCBLK(B2, 13);
  LOADBLK(B2, 15);  PROCBLK(A2, 14);
                    PROCBLK(B2, 15);
#undef PROCBLK
#undef LOADBLK
#undef WORD

  // Emit: slots 0..m-1 = kept ranks ascending; m..99 = non-kept ranks
  // ascending with score 0 (== ref top_k(kept_scores,100)).
  __shared__ u64 kw_s[16];
  __shared__ u32 cumk_s[17], cumn_s[17];
  if (lane == 0) {
    #pragma unroll
    for (int w = 0; w < 16; ++w) kw_s[w] = keptw[w];
  }
  __syncthreads();
  if (lane == 0) {
    u32 ck = 0, cn = 0;
    for (int w = 0; w < 16; ++w) {
      cumk_s[w] = ck; cumn_s[w] = cn;
      u64 rm = (w == 15) ? ((1ull << 40) - 1ull) : ~0ull;  // ranks 960..999
      ck += (u32)__popcll(kw_s[w] & rm);
      cn += (u32)__popcll(~kw_s[w] & rm);
    }
    cumk_s[16] = ck; cumn_s[16] = cn;
  }
  __syncthreads();
  const u32 mtot = cumk_s[16];

  for (int s = lane; s < 100; s += 64) {
    u32 r; float sc;
    if ((u32)s < mtot) {
      int w = 0;
      #pragma unroll
      for (int x = 1; x < 16; ++x) if (cumk_s[x] <= (u32)s) w = x;
      u64 rm = (w == 15) ? ((1ull << 40) - 1ull) : ~0ull;
      u64 word = kw_s[w] & rm;
      u32 b = (u32)s - cumk_s[w];
      for (u32 z = 0; z < b; ++z) word &= word - 1;
      r = (u32)(w * 64) + (u32)(__ffsll((long long)word) - 1);
      sc = scores_ws[n * NRANK + r];
    } else {
      u32 s2 = (u32)s - mtot;
      int w = 0;
      #pragma unroll
      for (int x = 1; x < 16; ++x) if (cumn_s[x] <= s2) w = x;
      u64 rm = (w == 15) ? ((1ull << 40) - 1ull) : ~0ull;
      u64 word = (~kw_s[w]) & rm;
      u32 b = s2 - cumn_s[w];
      for (u32 z = 0; z < b; ++z) word &= word - 1;
      r = (u32)(w * 64) + (u32)(__ffsll((long long)word) - 1);
      sc = 0.0f;
    }
    const float* bxp = boxes_ws + ((size_t)n * NRANK + r) * 4;
    float* o = out + ((size_t)n * 100 + s) * 6;
    o[0] = bxp[0]; o[1] = bxp[1]; o[2] = bxp[2]; o[3] = bxp[3];
    o[4] = sc; o[5] = 1.0f;
  }
}

// ---------------------------------------------------------------- launch
extern "C" void kernel_launch(void* const* d_in, const int* in_sizes, int n_in,
                              void* d_out, int out_size, void* d_ws, size_t ws_size,
                              hipStream_t stream) {
  (void)in_sizes; (void)n_in; (void)out_size;
  if (ws_size < WS_NEED) return;

  const float* box_cls = (const float*)d_in[1];
  const float* box_reg = (const float*)d_in[2];
  const int* imh = (const int*)d_in[4];
  const int* imw = (const int*)d_in[5];

  char* ws = (char*)d_ws;
  float* scores_ws = (float*)(ws + SCORES_OFF);
  u32*   valid_ws  = (u32*)(ws + VALID_OFF);
  float* boxes_ws  = (float*)(ws + BOXES_OFF);
  u64*   mask_ws   = (u64*)(ws + MASK_OFF);
  float* out = (float*)d_out;

  fcos_topk<<<N_IMG, 1024, 0, stream>>>(box_cls, box_reg, imh, imw,
                                        scores_ws, valid_ws, boxes_ws);
  dim3 gB(8, N_IMG);
  fcos_mask<<<gB, 1024, 0, stream>>>(boxes_ws, mask_ws);
  fcos_scan<<<N_IMG, 64, 0, stream>>>(scores_ws, valid_ws, boxes_ws, mask_ws, out);
}

// Round 7
// 157.071 us; speedup vs baseline: 1.4393x; 1.4393x over previous
//
#include <hip/hip_runtime.h>
#include <cstdint>

// FCOS post-processor, exact-semantics port of the JAX reference.
// N=32 images, C=1, H=100, W=168 -> 16800 locations; PRE_NMS=1000, POST=100.
//
//   K1 fcos_topk : per-image exact top-1000 (radix-select on unique 48-bit keys
//                  = sortable(sigmoid_f32) << 16 | (0xFFFF - idx)) + hybrid
//                  shfl/LDS bitonic sort + box decode/clip/validity.
//   K2 fcos_mask : pairwise IoU -> 64-bit suppression words, LOWER triangle +
//                  diagonal only (IoU exactly symmetric); column boxes hoisted
//                  to registers.
//   K3 fcos_scan : greedy NMS with ZERO shfl in the serial chain: within-block
//                  suppression set of kept box i = ballot(own_row_bit_i) by
//                  symmetry. ~25 cyc per kept box instead of ~150 (R5 post-
//                  mortem: L2-resident replays ran at identical 72us -> pure
//                  dependency-chain bound, shfl was the chain).

typedef unsigned long long u64;
typedef unsigned int u32;

#define HW_TOT 16800
#define W_GRID 168
#define K_PRE  1000
#define NRANK  1024
#define N_IMG  32

// ws layout (bytes)
#define SCORES_OFF 0
#define VALID_OFF  (N_IMG * NRANK * 4)
#define BOXES_OFF  (VALID_OFF + N_IMG * NRANK * 4)
#define MASK_OFF   (BOXES_OFF + N_IMG * NRANK * 16)
#define WS_NEED    ((size_t)MASK_OFF + (size_t)N_IMG * NRANK * 16 * 8)

// ---------------------------------------------------------------- kernel 1
__global__ __launch_bounds__(1024) void fcos_topk(
    const float* __restrict__ box_cls, const float* __restrict__ box_reg,
    const int* __restrict__ imh, const int* __restrict__ imw,
    float* __restrict__ scores_ws, u32* __restrict__ valid_ws,
    float* __restrict__ boxes_ws)
{
  const int n = blockIdx.x;
  const int t = threadIdx.x;
  __shared__ u32 hist[256];
  __shared__ u64 prefix_s;
  __shared__ u32 kneed_s, cnt_s;
  __shared__ u64 skey[1024];

  // Unique 48-bit keys; sigmoid in f64 then rounded (bit-exact vs ref,
  // absmax 0.0 in R1/R5). Low 16 bits 0xFFFF-idx => desc == lax.top_k order.
  u64 kreg[17];
  const float* cls = box_cls + (size_t)n * HW_TOT;
  #pragma unroll
  for (int k = 0; k < 17; ++k) {
    int i = t + k * 1024;
    u64 key = 0;
    if (i < HW_TOT) {
      float x = cls[i];
      double sd = 1.0 / (1.0 + exp(-(double)x));
      float s = (float)sd;
      u32 b = __float_as_uint(s);
      u32 u = (b & 0x80000000u) ? ~b : (b | 0x80000000u);
      key = ((u64)u << 16) | (u64)(0xFFFFu - (u32)i);
    }
    kreg[k] = key;
  }
  if (t == 0) { prefix_s = 0ull; kneed_s = K_PRE; cnt_s = 0u; }
  __syncthreads();

  // 6-pass MSB radix select. Plain LDS atomics (R5's ballot match-loop was a
  // measured regression: serial leader loop >> hashed atomic conflicts).
  for (int p = 5; p >= 0; --p) {
    if (t < 256) hist[t] = 0u;
    __syncthreads();
    const u64 pref = prefix_s;
    const int sh = p * 8;
    #pragma unroll
    for (int k = 0; k < 17; ++k) {
      u64 key = kreg[k];
      if ((key >> (sh + 8)) == pref)
        atomicAdd(&hist[(u32)((key >> sh) & 0xFFull)], 1u);
    }
    __syncthreads();
    if (t < 64) {  // inclusive suffix sum over 256 bins, single wave
      u32 h0 = hist[4*t], h1 = hist[4*t+1], h2 = hist[4*t+2], h3 = hist[4*t+3];
      u32 bs = h0 + h1 + h2 + h3, s = bs;
      #pragma unroll
      for (int off = 1; off < 64; off <<= 1) {
        u32 tmp = __shfl_down(s, off);
        if (t + off < 64) s += tmp;
      }
      u32 tail = s - bs;
      hist[4*t+3] = h3 + tail;
      hist[4*t+2] = h2 + h3 + tail;
      hist[4*t+1] = h1 + h2 + h3 + tail;
      hist[4*t]   = bs + tail;
    }
    __syncthreads();
    bool sel = false; u32 kn = 0, gt = 0;
    if (t < 256) {
      u32 ge = hist[t];
      gt = (t < 255) ? hist[t + 1] : 0u;
      kn = kneed_s;
      sel = (ge >= kn) && (gt < kn);
    }
    const u64 curp = prefix_s;
    __syncthreads();
    if (sel) { prefix_s = (curp << 8) | (u64)t; kneed_s = kn - gt; }
    __syncthreads();
  }

  // Compact keys >= T (unique keys -> exactly 1000), pad 0.
  const u64 T = prefix_s;
  skey[t] = 0ull;
  __syncthreads();
  #pragma unroll
  for (int k = 0; k < 17; ++k) {
    if (kreg[k] >= T) {
      u32 pos = atomicAdd(&cnt_s, 1u);
      if (pos < 1024u) skey[pos] = kreg[k];
    }
  }
  __syncthreads();

  // Hybrid bitonic sort desc: intra-wave via shfl_xor, cross-wave via LDS.
  u64 key = skey[t];
  #pragma unroll
  for (u32 k2 = 2; k2 <= 64; k2 <<= 1) {
    #pragma unroll
    for (u32 j = k2 >> 1; j > 0; j >>= 1) {
      u64 other = __shfl_xor(key, (int)j);
      bool takeMax = (((t & k2) == 0) == ((t & j) == 0));
      u64 mx = key > other ? key : other;
      u64 mn = key > other ? other : key;
      key = takeMax ? mx : mn;
    }
  }
  #pragma unroll
  for (u32 k2 = 128; k2 <= 1024; k2 <<= 1) {
    for (u32 j = k2 >> 1; j >= 64; j >>= 1) {
      skey[t] = key;
      __syncthreads();
      u64 other = skey[t ^ j];
      __syncthreads();
      bool takeMax = (((t & k2) == 0) == ((t & j) == 0));
      u64 mx = key > other ? key : other;
      u64 mn = key > other ? other : key;
      key = takeMax ? mx : mn;
    }
    #pragma unroll
    for (u32 j = 32; j > 0; j >>= 1) {
      u64 other = __shfl_xor(key, (int)j);
      bool takeMax = (((t & k2) == 0) == ((t & j) == 0));
      u64 mx = key > other ? key : other;
      u64 mn = key > other ? other : key;
      key = takeMax ? mx : mn;
    }
  }

  // Decode rank t (from register key).
  const float fw = (float)(*imw) - 1.0f;
  const float fh = (float)(*imh) - 1.0f;
  float* bx = boxes_ws + ((size_t)n * NRANK + t) * 4;
  if (t < K_PRE) {
    u32 u = (u32)(key >> 16);
    u32 b = (u & 0x80000000u) ? (u & 0x7FFFFFFFu) : ~u;
    float s = __uint_as_float(b);
    u32 idx = 0xFFFFu - (u32)(key & 0xFFFFull);
    int hh = (int)idx / W_GRID, ww = (int)idx - hh * W_GRID;
    float lx = (float)(ww * 8 + 4), ly = (float)(hh * 8 + 4);
    const float* rg = box_reg + (size_t)n * 4 * HW_TOT + idx;
    float r0 = rg[0], r1 = rg[HW_TOT], r2 = rg[2 * HW_TOT], r3 = rg[3 * HW_TOT];
    float x1 = fminf(fmaxf(lx - r0, 0.0f), fw);
    float y1 = fminf(fmaxf(ly - r1, 0.0f), fh);
    float x2 = fminf(fmaxf(lx + r2, 0.0f), fw);
    float y2 = fminf(fmaxf(ly + r3, 0.0f), fh);
    bool valid = (s > 0.01f) && ((x2 - x1 + 1.0f) >= 0.0f)
                             && ((y2 - y1 + 1.0f) >= 0.0f);   // MIN_SIZE = 0
    scores_ws[n * NRANK + t] = s;
    valid_ws[n * NRANK + t] = valid ? 1u : 0u;
    bx[0] = x1; bx[1] = y1; bx[2] = x2; bx[3] = y2;
  } else {
    scores_ws[n * NRANK + t] = 0.0f;
    valid_ws[n * NRANK + t] = 0u;
    bx[0] = 0.0f; bx[1] = 0.0f; bx[2] = 0.0f; bx[3] = 0.0f;
  }
}

// ---------------------------------------------------------------- kernel 2
// Lower-triangle + diagonal words only (c <= i>>6). Column boxes bj[c] and
// areas aj[c] are per-lane constants -> hoisted to registers once; inner loop
// is pure VALU. c-loop statically unrolled with uniform guard (rule #20:
// runtime-indexed register arrays would spill to scratch).
__global__ __launch_bounds__(1024) void fcos_mask(
    const float* __restrict__ boxes_ws, u64* __restrict__ mask_ws)
{
  const int n = blockIdx.y, g = blockIdx.x;   // g < 8
  const int t = threadIdx.x;
  __shared__ float4 bx[1024];
  bx[t] = ((const float4*)boxes_ws)[(size_t)n * NRANK + t];
  __syncthreads();
  const int wv = t >> 6, lane = t & 63;

  float4 bj[16]; float aj[16];
  #pragma unroll
  for (int c = 0; c < 16; ++c) {
    bj[c] = bx[c * 64 + lane];
    aj[c] = __fmul_rn(fmaxf(bj[c].z - bj[c].x, 0.0f), fmaxf(bj[c].w - bj[c].y, 0.0f));
  }

  u64* mimg = mask_ws + (size_t)n * NRANK * 16;
  for (int r = wv; r < 125; r += 16) {
    const int i = r * 8 + g;                  // covers 0..999 exactly once
    const float4 bi = bx[i];                  // uniform broadcast read
    const float ai = __fmul_rn(fmaxf(bi.z - bi.x, 0.0f), fmaxf(bi.w - bi.y, 0.0f));
    const int cmax = i >> 6;
    #pragma unroll
    for (int c = 0; c < 16; ++c) {
      if (c <= cmax) {                        // wave-uniform guard
        float iw  = fmaxf(fminf(bi.z, bj[c].z) - fmaxf(bi.x, bj[c].x), 0.0f);
        float ih2 = fmaxf(fminf(bi.w, bj[c].w) - fmaxf(bi.y, bj[c].y), 0.0f);
        float inter = __fmul_rn(iw, ih2);
        float uni = fmaxf(__fsub_rn(__fadd_rn(ai, aj[c]), inter), 1e-9f);
        float iou = inter / uni;
        u64 m = __ballot(iou > 0.5f);
        if (lane == 0) mimg[(size_t)i * 16 + c] = m;
      }
    }
  }
}

// ---------------------------------------------------------------- kernel 3
// Greedy scan, shfl-free serial chain. Lane j holds mask row blk*64+j.
// Cross-block: live = valid & ~ballot(OR_w<BV(row_w & keptw_w) != 0).
// Within-block: kept box i suppresses ballot(own-row bit i) by SYMMETRY of
// the intra-block 64x64 matrix (lane j's row bit i == iou(i,j) state).
// Chain per kept box: s_ff1 -> v_lshr -> v_cmp(ballot) -> s_andn2, no LDS.
__global__ __launch_bounds__(64) void fcos_scan(
    const float* __restrict__ scores_ws, const u32* __restrict__ valid_ws,
    const float* __restrict__ boxes_ws, const u64* __restrict__ mask_ws,
    float* __restrict__ out)
{
  const int n = blockIdx.x;
  const int lane = threadIdx.x;
  const u64* mbase = mask_ws + (size_t)n * NRANK * 16;

  u64 vw[16];
  #pragma unroll
  for (int w = 0; w < 16; ++w)
    vw[w] = __ballot(valid_ws[n * NRANK + w * 64 + lane] != 0u);

  u64 keptw[16];
  #pragma unroll
  for (int w = 0; w < 16; ++w) keptw[w] = 0ull;

  ulonglong2 A2[8], B2[8];
#define WORD(ARR, w) ((w) & 1 ? ARR[(w) >> 1].y : ARR[(w) >> 1].x)
#define LOADBLK(DST, BLK) do { \
    const ulonglong2* _p = (const ulonglong2*)(mbase + (((size_t)(BLK)) * 64 + (size_t)lane) * 16); \
    _Pragma("unroll") \
    for (int _r = 0; _r < 8; ++_r) DST[_r] = _p[_r]; \
  } while (0)
#define PROCBLK(ARR, BV) do { \
    u64 _acc = 0ull; \
    _Pragma("unroll") \
    for (int _w = 0; _w < 16; ++_w) \
      if (_w < (BV)) _acc |= WORD(ARR, _w) & keptw[_w]; \
    u64 _live = vw[(BV)] & ~__ballot(_acc != 0ull); \
    const u64 _intra = WORD(ARR, (BV)); \
    u64 _kb = 0ull; \
    while (_live) { \
      u32 _i = (u32)(__ffsll((long long)_live) - 1); \
      _kb |= (1ull << _i); \
      u64 _sup = __ballot(((_intra >> _i) & 1ull) != 0ull); \
      _live &= ~(_sup | (1ull << _i)); \
    } \
    keptw[(BV)] = _kb; \
  } while (0)

  LOADBLK(A2, 0);
  LOADBLK(B2, 1);   PROCBLK(A2, 0);
  LOADBLK(A2, 2);   PROCBLK(B2, 1);
  LOADBLK(B2, 3);   PROCBLK(A2, 2);
  LOADBLK(A2, 4);   PROCBLK(B2, 3);
  LOADBLK(B2, 5);   PROCBLK(A2, 4);
  LOADBLK(A2, 6);   PROCBLK(B2, 5);
  LOADBLK(B2, 7);   PROCBLK(A2, 6);
  LOADBLK(A2, 8);   PROCBLK(B2, 7);
  LOADBLK(B2, 9);   PROCBLK(A2, 8);
  LOADBLK(A2, 10);  PROCBLK(B2, 9);
  LOADBLK(B2, 11);  PROCBLK(A2, 10);
  LOADBLK(A2, 12);  PROCBLK(B2, 11);
  LOADBLK(B2, 13);  PROCBLK(A2, 12);
  LOADBLK(A2, 14);  PROCBLK(B2, 13);
  LOADBLK(B2, 15);  PROCBLK(A2, 14);
                    PROCBLK(B2, 15);
#undef PROCBLK
#undef LOADBLK
#undef WORD

  // Emit: slots 0..m-1 = kept ranks ascending; m..99 = non-kept ranks
  // ascending with score 0 (== ref top_k(kept_scores,100)).
  __shared__ u64 kw_s[16];
  __shared__ u32 cumk_s[17], cumn_s[17];
  if (lane == 0) {
    #pragma unroll
    for (int w = 0; w < 16; ++w) kw_s[w] = keptw[w];
  }
  __syncthreads();
  if (lane == 0) {
    u32 ck = 0, cn = 0;
    for (int w = 0; w < 16; ++w) {
      cumk_s[w] = ck; cumn_s[w] = cn;
      u64 rm = (w == 15) ? ((1ull << 40) - 1ull) : ~0ull;  // ranks 960..999
      ck += (u32)__popcll(kw_s[w] & rm);
      cn += (u32)__popcll(~kw_s[w] & rm);
    }
    cumk_s[16] = ck; cumn_s[16] = cn;
  }
  __syncthreads();
  const u32 mtot = cumk_s[16];

  for (int s = lane; s < 100; s += 64) {
    u32 r; float sc;
    if ((u32)s < mtot) {
      int w = 0;
      #pragma unroll
      for (int x = 1; x < 16; ++x) if (cumk_s[x] <= (u32)s) w = x;
      u64 rm = (w == 15) ? ((1ull << 40) - 1ull) : ~0ull;
      u64 word = kw_s[w] & rm;
      u32 b = (u32)s - cumk_s[w];
      for (u32 z = 0; z < b; ++z) word &= word - 1;
      r = (u32)(w * 64) + (u32)(__ffsll((long long)word) - 1);
      sc = scores_ws[n * NRANK + r];
    } else {
      u32 s2 = (u32)s - mtot;
      int w = 0;
      #pragma unroll
      for (int x = 1; x < 16; ++x) if (cumn_s[x] <= s2) w = x;
      u64 rm = (w == 15) ? ((1ull << 40) - 1ull) : ~0ull;
      u64 word = (~kw_s[w]) & rm;
      u32 b = s2 - cumn_s[w];
      for (u32 z = 0; z < b; ++z) word &= word - 1;
      r = (u32)(w * 64) + (u32)(__ffsll((long long)word) - 1);
      sc = 0.0f;
    }
    const float* bxp = boxes_ws + ((size_t)n * NRANK + r) * 4;
    float* o = out + ((size_t)n * 100 + s) * 6;
    o[0] = bxp[0]; o[1] = bxp[1]; o[2] = bxp[2]; o[3] = bxp[3];
    o[4] = sc; o[5] = 1.0f;
  }
}

// ---------------------------------------------------------------- launch
extern "C" void kernel_launch(void* const* d_in, const int* in_sizes, int n_in,
                              void* d_out, int out_size, void* d_ws, size_t ws_size,
                              hipStream_t stream) {
  (void)in_sizes; (void)n_in; (void)out_size;
  if (ws_size < WS_NEED) return;

  const float* box_cls = (const float*)d_in[1];
  const float* box_reg = (const float*)d_in[2];
  const int* imh = (const int*)d_in[4];
  const int* imw = (const int*)d_in[5];

  char* ws = (char*)d_ws;
  float* scores_ws = (float*)(ws + SCORES_OFF);
  u32*   valid_ws  = (u32*)(ws + VALID_OFF);
  float* boxes_ws  = (float*)(ws + BOXES_OFF);
  u64*   mask_ws   = (u64*)(ws + MASK_OFF);
  float* out = (float*)d_out;

  fcos_topk<<<N_IMG, 1024, 0, stream>>>(box_cls, box_reg, imh, imw,
                                        scores_ws, valid_ws, boxes_ws);
  dim3 gB(8, N_IMG);
  fcos_mask<<<gB, 1024, 0, stream>>>(boxes_ws, mask_ws);
  fcos_scan<<<N_IMG, 64, 0, stream>>>(scores_ws, valid_ws, boxes_ws, mask_ws, out);
}